// Round 1
// baseline (153.433 us; speedup 1.0000x reference)
//
#include <hip/hip_runtime.h>
#include <math.h>

#define N_NODES 8192
#define C_CLS   16
#define JC      512   // j-chunk staged in LDS per iteration

// ---- workspace layout (bytes) ----
#define WS_INPUTS 0              // 8192*16*4  = 524288
#define WS_HPART  524288         // 512*256*4  = 524288
#define WS_IDX    1048576        // 8192*4     = 32768
#define WS_COUNTS 1081344        // 16*4
#define WS_NM     1081408        // 4

// ---------------------------------------------------------------------------
// A1: inputs = softmax(init_inputs) blended with one-hot(y) on masked rows
// ---------------------------------------------------------------------------
__global__ void k_inputs(const float* __restrict__ init_in,
                         const int* __restrict__ y,
                         const int* __restrict__ mask,
                         float* __restrict__ inputs) {
  int i = blockIdx.x * blockDim.x + threadIdx.x;
  if (i >= N_NODES) return;
  const float4* p = (const float4*)(init_in + (size_t)i * C_CLS);
  float v[16];
  float4 a0 = p[0], a1 = p[1], a2 = p[2], a3 = p[3];
  v[0]=a0.x; v[1]=a0.y; v[2]=a0.z; v[3]=a0.w;
  v[4]=a1.x; v[5]=a1.y; v[6]=a1.z; v[7]=a1.w;
  v[8]=a2.x; v[9]=a2.y; v[10]=a2.z; v[11]=a2.w;
  v[12]=a3.x; v[13]=a3.y; v[14]=a3.z; v[15]=a3.w;
  float mx = v[0];
#pragma unroll
  for (int c = 1; c < 16; ++c) mx = fmaxf(mx, v[c]);
  float s = 0.f;
#pragma unroll
  for (int c = 0; c < 16; ++c) { v[c] = expf(v[c] - mx); s += v[c]; }
  float inv = 1.0f / s;
  if (mask[i] != 0) {
    int yc = y[i];
#pragma unroll
    for (int c = 0; c < 16; ++c) v[c] = (c == yc) ? 1.0f : 0.0f;
  } else {
#pragma unroll
    for (int c = 0; c < 16; ++c) v[c] *= inv;
  }
  float4* o = (float4*)(inputs + (size_t)i * C_CLS);
  o[0] = make_float4(v[0], v[1], v[2], v[3]);
  o[1] = make_float4(v[4], v[5], v[6], v[7]);
  o[2] = make_float4(v[8], v[9], v[10], v[11]);
  o[3] = make_float4(v[12], v[13], v[14], v[15]);
}

// ---------------------------------------------------------------------------
// A2: deterministic compaction of masked row indices + per-class counts
// ---------------------------------------------------------------------------
__global__ void k_compact(const int* __restrict__ y,
                          const int* __restrict__ mask,
                          int* __restrict__ idx,
                          int* __restrict__ counts,
                          int* __restrict__ nmp) {
  __shared__ int cnt[256];
  __shared__ int pref[256];
  __shared__ int cls[16];
  int t = threadIdx.x;
  if (t < 16) cls[t] = 0;
  int base = t * 32;
  int c = 0;
  for (int k = 0; k < 32; ++k) c += (mask[base + k] != 0);
  cnt[t] = c;
  __syncthreads();
  if (t == 0) {
    int run = 0;
    for (int i = 0; i < 256; ++i) { pref[i] = run; run += cnt[i]; }
  }
  __syncthreads();
  int w = pref[t];
  for (int k = 0; k < 32; ++k) {
    int r = base + k;
    if (mask[r] != 0) {
      idx[w++] = r;
      atomicAdd(&cls[y[r]], 1);   // int atomics: order-independent, deterministic
    }
  }
  __syncthreads();
  if (t < 16) counts[t] = cls[t];
  if (t == 0) nmp[0] = pref[255] + cnt[255];
}

// ---------------------------------------------------------------------------
// B: fused rowsum + (A-row @ inputs) for masked rows, per-block H partials.
// 4 waves/block, 4 rows/wave. inputs chunk staged in LDS with XOR-swizzled
// 16B granules so ds_read_b128 is conflict-free (8 lanes per slot class).
// ---------------------------------------------------------------------------
__global__ __launch_bounds__(256) void k_main(const float* __restrict__ A,
                                              const float* __restrict__ inputs,
                                              const int* __restrict__ idx,
                                              const int* __restrict__ nmp,
                                              const int* __restrict__ y,
                                              float* __restrict__ Hpart) {
  __shared__ float lin[JC * 16];       // 32 KiB staged inputs chunk (swizzled)
  __shared__ float hp[4][16][16];      // per-wave H partials
  int tid = threadIdx.x, wid = tid >> 6, lane = tid & 63;
  int nm = *nmp;
  int bid = blockIdx.x;
  if (bid * 16 >= nm) return;          // whole-block uniform: no barrier issues

  ((float*)hp)[tid] = 0.f; ((float*)hp)[tid + 256] = 0.f;
  ((float*)hp)[tid + 512] = 0.f; ((float*)hp)[tid + 768] = 0.f;

  int rbase = bid * 16 + wid * 4;
  int rows[4]; bool valid[4];
  const float* arow[4];
#pragma unroll
  for (int r = 0; r < 4; ++r) {
    int g = rbase + r;
    valid[r] = (g < nm);
    rows[r] = valid[r] ? idx[g] : 0;
    arow[r] = A + (size_t)rows[r] * N_NODES;
  }

  float acc[4][16];
  float asum[4] = {0.f, 0.f, 0.f, 0.f};
#pragma unroll
  for (int r = 0; r < 4; ++r)
#pragma unroll
    for (int c = 0; c < 16; ++c) acc[r][c] = 0.f;

  for (int ch = 0; ch < N_NODES / JC; ++ch) {
    int j0 = ch * JC;
    // stage: granule G = jloc*4 + c4 -> slot G ^ ((G>>4)&7)
#pragma unroll
    for (int s = 0; s < (JC * 16) / (256 * 4); ++s) {
      int G = s * 256 + tid;
      float4 v = *(const float4*)(inputs + (size_t)j0 * 16 + (size_t)G * 4);
      int slot = G ^ ((G >> 4) & 7);
      *(float4*)(lin + slot * 4) = v;
    }
    __syncthreads();
#pragma unroll
    for (int st = 0; st < JC / 256; ++st) {
      int jl = st * 256 + lane * 4;
      float4 a4[4];
#pragma unroll
      for (int r = 0; r < 4; ++r) {
        if (valid[r]) a4[r] = *(const float4*)(arow[r] + j0 + jl);
        else a4[r] = make_float4(0.f, 0.f, 0.f, 0.f);
      }
#pragma unroll
      for (int jj = 0; jj < 4; ++jj) {
        int g0 = (jl + jj) * 4;
        int sw = lane & 7;             // == ((jl+jj)>>2)&7
        float in[16];
#pragma unroll
        for (int c4 = 0; c4 < 4; ++c4) {
          float4 v = *(const float4*)(lin + ((g0 + c4) ^ sw) * 4);
          in[c4 * 4 + 0] = v.x; in[c4 * 4 + 1] = v.y;
          in[c4 * 4 + 2] = v.z; in[c4 * 4 + 3] = v.w;
        }
#pragma unroll
        for (int r = 0; r < 4; ++r) {
          float av = (jj == 0) ? a4[r].x : (jj == 1) ? a4[r].y
                   : (jj == 2) ? a4[r].z : a4[r].w;
          asum[r] += av;
#pragma unroll
          for (int c = 0; c < 16; ++c) acc[r][c] = fmaf(av, in[c], acc[r][c]);
        }
      }
    }
    __syncthreads();
  }

  // epilogue: reduce across 64 lanes, normalize by rowsum, scatter to class
#pragma unroll
  for (int r = 0; r < 4; ++r) {
    if (!valid[r]) continue;           // wave-uniform
    float s = asum[r];
    float t16[16];
#pragma unroll
    for (int c = 0; c < 16; ++c) t16[c] = acc[r][c];
    for (int m = 1; m < 64; m <<= 1) {
      s += __shfl_xor(s, m, 64);
#pragma unroll
      for (int c = 0; c < 16; ++c) t16[c] += __shfl_xor(t16[c], m, 64);
    }
    float invs = 1.0f / s;
    int cls_r = y[rows[r]];
    if (lane < 16) hp[wid][cls_r][lane] += t16[lane] * invs;
  }
  __syncthreads();
  int a = tid >> 4, cc = tid & 15;
  float o = hp[0][a][cc] + hp[1][a][cc] + hp[2][a][cc] + hp[3][a][cc];
  Hpart[(size_t)bid * 256 + tid] = o;
}

// ---------------------------------------------------------------------------
// C: reduce partials, divide by counts, NaN repair, single-wave Sinkhorn
// ---------------------------------------------------------------------------
__global__ void k_final(const float* __restrict__ Hpart,
                        const int* __restrict__ counts,
                        const int* __restrict__ nmp,
                        float* __restrict__ out) {
  __shared__ float S[256];
  __shared__ float S2[256];
  __shared__ float Sn[256];
  __shared__ float rs[16];
  __shared__ int nc[16];
  int t = threadIdx.x;
  int a = t >> 4, c = t & 15;
  int nm = *nmp;
  int nb = (nm + 15) >> 4;
  float s = 0.f;
  for (int b = 0; b < nb; ++b) s += Hpart[(size_t)b * 256 + t];
  float cnt = (float)counts[a];
  float H = s / cnt;                    // 0/0 -> NaN, matches reference
  S[t] = H;
  __syncthreads();
  float HT = S[c * 16 + a];
  if (isnan(H)) H = HT;
  bool nan2 = isnan(H);
  float Hz = nan2 ? 0.f : H;
  S2[t] = Hz;
  Sn[t] = nan2 ? 1.f : 0.f;
  __syncthreads();
  if (t < 16) {
    float rsum = 0.f, ns = 0.f;
    for (int k = 0; k < 16; ++k) { rsum += S2[t * 16 + k]; ns += Sn[t * 16 + k]; }
    rs[t] = rsum; nc[t] = (int)ns;
  }
  __syncthreads();
  float miss = (1.0f - rs[a]) / (float)max(nc[a], 1);
  H = nan2 ? miss : Hz;
  __syncthreads();
  S[t] = H;
  __syncthreads();
  // single-wave Sinkhorn: lane holds col c, rows rg*4+k
  if (t < 64) {
    int lane = t;
    int col = lane & 15, rg = lane >> 4;
    float h[4];
#pragma unroll
    for (int k = 0; k < 4; ++k) h[k] = S[(rg * 4 + k) * 16 + col];
    for (int it = 0; it < 3000; ++it) {
      float p0 = h[0], p1 = h[1], p2 = h[2], p3 = h[3];
      // column sums (over 16 rows)
      float cs = h[0] + h[1] + h[2] + h[3];
      cs += __shfl_xor(cs, 16, 64);
      cs += __shfl_xor(cs, 32, 64);
#pragma unroll
      for (int k = 0; k < 4; ++k) h[k] = h[k] / cs;
      // row sums (over 16 cols)
#pragma unroll
      for (int k = 0; k < 4; ++k) {
        float rv = h[k];
        rv += __shfl_xor(rv, 1, 64);
        rv += __shfl_xor(rv, 2, 64);
        rv += __shfl_xor(rv, 4, 64);
        rv += __shfl_xor(rv, 8, 64);
        h[k] = h[k] / rv;
      }
      float d = fabsf(h[0] - p0) + fabsf(h[1] - p1) +
                fabsf(h[2] - p2) + fabsf(h[3] - p3);
      d += __shfl_xor(d, 1, 64);  d += __shfl_xor(d, 2, 64);
      d += __shfl_xor(d, 4, 64);  d += __shfl_xor(d, 8, 64);
      d += __shfl_xor(d, 16, 64); d += __shfl_xor(d, 32, 64);
      if (d < 1e-6f) break;       // ref TOL=1e-12 == exact fixed point; any
                                  // residual wiggle is ulp-scale << 1.25e-3
    }
#pragma unroll
    for (int k = 0; k < 4; ++k) out[(rg * 4 + k) * 16 + col] = h[k];
  }
}

// ---------------------------------------------------------------------------
extern "C" void kernel_launch(void* const* d_in, const int* in_sizes, int n_in,
                              void* d_out, int out_size, void* d_ws, size_t ws_size,
                              hipStream_t stream) {
  const float* A       = (const float*)d_in[0];  // raw_adj  (8192*8192)
  const float* init_in = (const float*)d_in[1];  // init_inputs (8192*16)
  const int*   y       = (const int*)d_in[2];    // (8192)
  const int*   mask    = (const int*)d_in[3];    // (8192)
  float* out = (float*)d_out;                    // (16*16)
  char*  ws  = (char*)d_ws;
  float* inputs = (float*)(ws + WS_INPUTS);
  float* Hpart  = (float*)(ws + WS_HPART);
  int*   idx    = (int*)(ws + WS_IDX);
  int*   counts = (int*)(ws + WS_COUNTS);
  int*   nmp    = (int*)(ws + WS_NM);

  k_inputs<<<N_NODES / 256, 256, 0, stream>>>(init_in, y, mask, inputs);
  k_compact<<<1, 256, 0, stream>>>(y, mask, idx, counts, nmp);
  k_main<<<512, 256, 0, stream>>>(A, inputs, idx, nmp, y, Hpart);
  k_final<<<1, 256, 0, stream>>>(Hpart, counts, nmp, out);
}